// Round 9
// baseline (226.125 us; speedup 1.0000x reference)
//
#include <hip/hip_runtime.h>
#include <hip/hip_bf16.h>
#include <stdint.h>

// out[4096,4096] = x[4096,2048] @ matrix[0,4096,2048]^T   (fp32 in/out)
// R12: FUSED CAST -- the separate f32->bf16 pass (96MB, ~17us) is deleted;
// the GEMM stages f32 directly: global f32 -> regs -> f2bf (bit-identical
// to the old cast kernel -> absmax unchanged) -> swizzled ds_write_b128.
// Rationale: gemm is pinned ~67us across R3-R11 (LDS+MFMA pipes both near-
// binding); the cast pass is the remaining controllable time. Reg-staging
// also enables full LDS double-buffer (96KB, 1 block/CU, 8 waves): staging
// loads ride through raw s_barrier (no vmcnt drain, T14 issue-early/
// write-late), ONE barrier+lgkm(0) per K-tile. Inner loop/fragment layout/
// XOR chunk swizzle (0 conflicts)/m89 C/D epilogue = R11's, unchanged.

#define LAS __attribute__((address_space(3)))

typedef __bf16 bf16x8 __attribute__((ext_vector_type(8)));
typedef unsigned short u16x8 __attribute__((ext_vector_type(8)));
typedef float f32x4 __attribute__((ext_vector_type(4)));

static __device__ __forceinline__ unsigned short f2bf(float f) {
  union { float f; uint32_t u; } a; a.f = f;
  uint32_t u = a.u;
  u += 0x7FFFu + ((u >> 16) & 1u);   // round-to-nearest-even (matches old cast)
  return (unsigned short)(u >> 16);
}

static __device__ __forceinline__ bf16x8 cvt8(float4 lo, float4 hi) {
  u16x8 r;
  r[0] = f2bf(lo.x); r[1] = f2bf(lo.y); r[2] = f2bf(lo.z); r[3] = f2bf(lo.w);
  r[4] = f2bf(hi.x); r[5] = f2bf(hi.y); r[6] = f2bf(hi.z); r[7] = f2bf(hi.w);
  union { u16x8 u; bf16x8 b; } c; c.u = r; return c.b;
}

#define MFMA16(a, b, c) __builtin_amdgcn_mfma_f32_16x16x32_bf16((a), (b), (c), 0, 0, 0)
#define SB0 __builtin_amdgcn_sched_barrier(0)

// C[M,N] = A[M,K]*B[N,K]^T, M=N=4096, K=2048 (A,B fp32). 512 thr = 8 waves.
// Block tile 256x128; wave (wr=wave>>1, wc=wave&1) owns rows wr*64..+64,
// cols wc*64..+64 as acc[4][4] of 16x16x32 frags. BK=64, NT=32.
// LDS: As[2][256*64]+Bs[2][128*64] bf16 dbuf (96KB -> 1 block/CU). Layout
// identical to R11: row r's global 16B-chunk c stored at physical c^(r&7).
// Staging per wave per tile: A rows [wave*32,+32) 4 units, B rows
// [wave*16,+16) 2 units; unit u: lane -> row u*8+lr, f32 cols lc*8..+8
// (two float4 loads), cvt8 -> one ds_write_b128 to buf p^1.
// Per tile t (p=t&1): compute ks0 | issue f32 loads(t+1) | compute ks1 |
// cvt+write(t+1)->p^1 | lgkm(0); s_barrier.   (1 barrier/tile; loads stay
// in flight across it -- raw barrier, no vmcnt drain.)
__global__ __launch_bounds__(512, 2)
void gemm_bt_fused(const float* __restrict__ A,
                   const float* __restrict__ B,
                   float* __restrict__ C) {
  constexpr int K  = 2048;
  constexpr int N  = 4096;
  constexpr int NT = K / 64;   // 32 K-tiles

  __shared__ __align__(16) unsigned short As[2][256 * 64];   // 64 KB
  __shared__ __align__(16) unsigned short Bs[2][128 * 64];   // 32 KB

  const int tid  = threadIdx.x;
  const int wave = tid >> 6;
  const int lane = tid & 63;
  const int wr   = wave >> 1;   // 0..3 (64-row block)
  const int wc   = wave & 1;    // 0..1 (64-col block)
  const int bM   = blockIdx.y * 256;
  const int bN   = blockIdx.x * 128;

  const int quad = lane >> 4;   // 0..3
  const int l15  = lane & 15;
  const int mx   = l15 & 7;

  // Staging addressing: lane -> row lr (of 8), pre-swizzled chunk lc.
  const int lr = lane >> 3;
  const int lc = (lane & 7) ^ lr;
  const float* aS = A + (size_t)(bM + wave * 32 + lr) * K + lc * 8;
  const float* bS = B + (size_t)(bN + wave * 16 + lr) * K + lc * 8;
  const int aL = wave * 32 * 64;   // LDS elem base (A)
  const int bL = wave * 16 * 64;   // LDS elem base (B)

  // Fragment read offsets: physical chunk = (ks*4+quad)^mx.
  const int aOff = (wr * 64 + l15) * 64;
  const int bOff = (wc * 64 + l15) * 64;

  f32x4 acc[4][4] = {};
  float4 fa[4][2], fb[2][2];

#define LOADS(tau) do {                                                        \
    const size_t kk_ = (size_t)(tau) * 64;                                     \
    _Pragma("unroll")                                                          \
    for (int u = 0; u < 4; ++u) {                                              \
      fa[u][0] = *(const float4*)(aS + (size_t)u * 8 * K + kk_);               \
      fa[u][1] = *(const float4*)(aS + (size_t)u * 8 * K + kk_ + 4);           \
    }                                                                          \
    _Pragma("unroll")                                                          \
    for (int u = 0; u < 2; ++u) {                                              \
      fb[u][0] = *(const float4*)(bS + (size_t)u * 8 * K + kk_);               \
      fb[u][1] = *(const float4*)(bS + (size_t)u * 8 * K + kk_ + 4);           \
    }                                                                          \
  } while (0)

#define CVT_WRITE(pp) do {                                                     \
    _Pragma("unroll")                                                          \
    for (int u = 0; u < 4; ++u)                                                \
      *(bf16x8*)(As[pp] + aL + u * 512 + lane * 8) = cvt8(fa[u][0], fa[u][1]); \
    _Pragma("unroll")                                                          \
    for (int u = 0; u < 2; ++u)                                                \
      *(bf16x8*)(Bs[pp] + bL + u * 512 + lane * 8) = cvt8(fb[u][0], fb[u][1]); \
  } while (0)

  // Prologue: tile 0 -> buf 0.
  LOADS(0);
  CVT_WRITE(0);
  asm volatile("s_waitcnt lgkmcnt(0)" ::: "memory");
  SB0;
  __builtin_amdgcn_s_barrier();
  SB0;

#pragma unroll 1
  for (int t = 0; t < NT; ++t) {
    const int p = t & 1;
    const unsigned short* Ap = As[p];
    const unsigned short* Bp = Bs[p];

    // ---- compute ks0 ----
    {
      const int koff = ((0 * 4 + quad) ^ mx) << 3;
      bf16x8 bF[4];
#pragma unroll
      for (int j = 0; j < 4; ++j)
        bF[j] = *(const bf16x8*)(Bp + bOff + j * 1024 + koff);
#pragma unroll
      for (int i = 0; i < 4; ++i) {
        const bf16x8 aF = *(const bf16x8*)(Ap + aOff + i * 1024 + koff);
#pragma unroll
        for (int j = 0; j < 4; ++j)
          acc[i][j] = MFMA16(aF, bF[j], acc[i][j]);
      }
    }
    // ---- issue next tile's f32 loads (long-latency; hidden under ks1) ----
    if (t + 1 < NT) LOADS(t + 1);
    // ---- compute ks1 ----
    {
      const int koff = ((1 * 4 + quad) ^ mx) << 3;
      bf16x8 bF[4];
#pragma unroll
      for (int j = 0; j < 4; ++j)
        bF[j] = *(const bf16x8*)(Bp + bOff + j * 1024 + koff);
#pragma unroll
      for (int i = 0; i < 4; ++i) {
        const bf16x8 aF = *(const bf16x8*)(Ap + aOff + i * 1024 + koff);
#pragma unroll
        for (int j = 0; j < 4; ++j)
          acc[i][j] = MFMA16(aF, bF[j], acc[i][j]);
      }
    }
    // ---- cvt + write tile t+1 into buf p^1 (its readers finished compute
    //      of tile t-1 before this tile's entry barrier -> WAR-safe) ----
    if (t + 1 < NT) CVT_WRITE(p ^ 1);
    // ---- single sync point: my ds ops done; publish buf p^1, free buf p ----
    asm volatile("s_waitcnt lgkmcnt(0)" ::: "memory");
    SB0;
    __builtin_amdgcn_s_barrier();
    SB0;
  }
#undef LOADS
#undef CVT_WRITE

  // Epilogue: C/D layout col=lane&15, row=quad*4+reg (m89-verified).
#pragma unroll
  for (int i = 0; i < 4; ++i) {
    const int row0 = bM + wr * 64 + i * 16 + quad * 4;
#pragma unroll
    for (int j = 0; j < 4; ++j) {
      const int col = bN + wc * 64 + j * 16 + l15;
#pragma unroll
      for (int t = 0; t < 4; ++t)
        C[(size_t)(row0 + t) * N + col] = acc[i][j][t];
    }
  }
}

extern "C" void kernel_launch(void* const* d_in, const int* in_sizes, int n_in,
                              void* d_out, int out_size, void* d_ws, size_t ws_size,
                              hipStream_t stream) {
  const float* x   = (const float*)d_in[0];   // [4096, 2048]
  const float* mat = (const float*)d_in[1];   // [1, 4096, 2048]
  float* out = (float*)d_out;                 // [4096, 4096]

  // Single fused kernel: no cast pass, no workspace.
  // 512 blocks: grid.x = N/128 = 32, grid.y = M/256 = 16; 1 block/CU (96KB
  // LDS), 2 passes/CU. Natural order: concurrent blocks on an XCD share the
  // same A row-panel (L2-resident); B panels served from L3.
  gemm_bt_fused<<<dim3(32, 16), 512, 0, stream>>>(x, mat, out);
}

// Round 10
// 172.411 us; speedup vs baseline: 1.3115x; 1.3115x over previous
//
#include <hip/hip_runtime.h>
#include <hip/hip_bf16.h>
#include <stdint.h>

// out[4096,4096] = x[4096,2048] @ matrix[0,4096,2048]^T   (fp32 in/out)
// R13: cast pass restored (R12's fusion re-read f32 per block: FETCH 74->190MB,
// MfmaUtil 17% -- reverted). GEMM continues R11's winning axis (partition
// granularity): block tile halved to 128x128, 4 waves of 64x64, 32KB
// single-buffered LDS, grid 32x32=1024 -> 4 blocks/CU (launch_bounds(256,4)).
// Mechanism: R3->R11 (+3%) came from more independent contexts hiding the
// per-tile stage drain; 4 independent 4-wave barrier groups per CU interleave
// finer than 2x8. Guide's tile table for this structure family also ranks
// 128^2 first. Inner loop / XOR chunk swizzle (0 conflicts) / m89 C/D layout
// unchanged from R11.

#define GAS __attribute__((address_space(1)))
#define LAS __attribute__((address_space(3)))

typedef __bf16 bf16x8 __attribute__((ext_vector_type(8)));
typedef float f32x4 __attribute__((ext_vector_type(4)));

static __device__ __forceinline__ unsigned short f2bf(float f) {
  union { float f; uint32_t u; } a; a.f = f;
  uint32_t u = a.u;
  u += 0x7FFFu + ((u >> 16) & 1u);   // round-to-nearest-even
  return (unsigned short)(u >> 16);
}

__global__ void cvt_f32_to_bf16(const float4* __restrict__ x,
                                const float4* __restrict__ m,
                                ushort4* __restrict__ xo,
                                ushort4* __restrict__ mo) {
  const int i = blockIdx.x * blockDim.x + threadIdx.x;
  const float4* __restrict__ src = blockIdx.y ? m : x;
  ushort4* __restrict__ dst      = blockIdx.y ? mo : xo;
  float4 v = src[i];
  ushort4 o;
  o.x = f2bf(v.x); o.y = f2bf(v.y); o.z = f2bf(v.z); o.w = f2bf(v.w);
  dst[i] = o;
}

#define MFMA16(a, b, c) __builtin_amdgcn_mfma_f32_16x16x32_bf16((a), (b), (c), 0, 0, 0)

// C[M,N] = A[M,K]*B[N,K]^T, M=N=4096, K=2048. 256 threads = 4 waves.
// Block tile 128x128; wave (wr=wave>>1, wc=wave&1) owns rows wr*64..+64,
// cols wc*64..+64 as acc[4][4] of 16x16x32 frags. BK=64, NT=32.
// LDS: As[128*64]+Bs[128*64] single-buffered (32KB); global 16B-chunk c of
// row r stored at physical chunk c^(r&7).
// Per K-tile: stage (4A+4B gload_lds per wave) | sync | 2 ks x {read bF[4],
// {read aF_i; 4 MFMA} x4} | sync.  4 blocks/CU x 4 waves = 4 waves/SIMD,
// from 4 INDEPENDENT blocks (finest stall interleave in this family).
__global__ __launch_bounds__(256, 4)
void gemm_bt_bf16(const unsigned short* __restrict__ A,
                  const unsigned short* __restrict__ B,
                  float* __restrict__ C) {
  constexpr int K = 2048;
  constexpr int N = 4096;

  __shared__ __align__(16) unsigned short As[128 * 64];   // 16 KB
  __shared__ __align__(16) unsigned short Bs[128 * 64];   // 16 KB

  const int tid  = threadIdx.x;
  const int wave = tid >> 6;
  const int lane = tid & 63;
  const int wr   = wave >> 1;   // 0..1 (64-row block)
  const int wc   = wave & 1;    // 0..1 (64-col block)
  const int bM   = blockIdx.y * 128;
  const int bN   = blockIdx.x * 128;

  const int quad = lane >> 4;   // 0..3
  const int l15  = lane & 15;
  const int mx   = l15 & 7;     // = row&7 for all fragment rows (x16 offsets)

  // Staging: wave w covers A rows [w*32, w*32+32) and B rows [w*32, w*32+32),
  // 4 insts each (8 rows/inst). lane -> row lr, pre-swizzled chunk lc.
  const int lr = lane >> 3;
  const int lc = (lane & 7) ^ lr;
  const size_t aBase = (size_t)(bM + wave * 32 + lr) * K + lc * 8;
  const size_t bBase = (size_t)(bN + wave * 32 + lr) * K + lc * 8;
  const int aLds = wave * 32 * 64;   // elems
  const int bLds = wave * 32 * 64;

  // Fragment read offsets (elems). Physical chunk = (ks*4+quad)^mx.
  // Fragment row = wr*64 + i*16 + l15 -> row&7 == l15&7 == mx.
  const int aOff = (wr * 64 + l15) * 64;
  const int bOff = (wc * 64 + l15) * 64;

  f32x4 acc[4][4] = {};

  for (int k0 = 0; k0 < K; k0 += 64) {
#pragma unroll
    for (int t = 0; t < 4; ++t)
      __builtin_amdgcn_global_load_lds((const GAS void*)(A + aBase + k0 + t * 8 * K),
                                       (LAS void*)(As + aLds + t * 512), 16, 0, 0);
#pragma unroll
    for (int t = 0; t < 4; ++t)
      __builtin_amdgcn_global_load_lds((const GAS void*)(B + bBase + k0 + t * 8 * K),
                                       (LAS void*)(Bs + bLds + t * 512), 16, 0, 0);
    __syncthreads();

#pragma unroll
    for (int ks = 0; ks < 2; ++ks) {
      const int koff = ((ks * 4 + quad) ^ mx) << 3;
      bf16x8 bF[4];
#pragma unroll
      for (int j = 0; j < 4; ++j)
        bF[j] = *(const bf16x8*)(Bs + bOff + j * 1024 + koff);
#pragma unroll
      for (int i = 0; i < 4; ++i) {
        const bf16x8 aF = *(const bf16x8*)(As + aOff + i * 1024 + koff);
#pragma unroll
        for (int j = 0; j < 4; ++j)
          acc[i][j] = MFMA16(aF, bF[j], acc[i][j]);
      }
    }
    __syncthreads();
  }

  // Epilogue: C/D layout col=lane&15, row=quad*4+reg (m89-verified).
#pragma unroll
  for (int i = 0; i < 4; ++i) {
    const int row0 = bM + wr * 64 + i * 16 + quad * 4;
#pragma unroll
    for (int j = 0; j < 4; ++j) {
      const int col = bN + wc * 64 + j * 16 + l15;
#pragma unroll
      for (int t = 0; t < 4; ++t)
        C[(size_t)(row0 + t) * N + col] = acc[i][j][t];
    }
  }
}

extern "C" void kernel_launch(void* const* d_in, const int* in_sizes, int n_in,
                              void* d_out, int out_size, void* d_ws, size_t ws_size,
                              hipStream_t stream) {
  const float* x   = (const float*)d_in[0];   // [4096, 2048]
  const float* mat = (const float*)d_in[1];   // [1, 4096, 2048]
  float* out = (float*)d_out;                 // [4096, 4096]

  constexpr size_t ELEMS = 4096ull * 2048ull;
  unsigned short* xb = (unsigned short*)d_ws;
  unsigned short* mb = xb + ELEMS;

  dim3 cgrid((unsigned)(ELEMS / 4 / 256), 2);
  cvt_f32_to_bf16<<<cgrid, 256, 0, stream>>>((const float4*)x, (const float4*)mat,
                                             (ushort4*)xb, (ushort4*)mb);

  // 1024 blocks: grid 32x32 of 128x128 tiles -> 4 blocks/CU, 16 waves/CU,
  // 4 waves/SIMD from 4 independent blocks.
  gemm_bt_bf16<<<dim3(32, 32), 256, 0, stream>>>(xb, mb, out);
}